// Round 14
// baseline (508.138 us; speedup 1.0000x reference)
//
#include <hip/hip_runtime.h>
#include <hip/hip_bf16.h>
#include <math.h>

#define BSZ 4
#define NPT 4096
#define CH  192
#define KNB 16
#define KPH 20              // kept per half
#define KCAND (2 * KPH)     // refine candidates
#define NTOT ((float)(BSZ * NPT))

typedef short short8 __attribute__((ext_vector_type(8)));
typedef float f32x4  __attribute__((ext_vector_type(4)));

__device__ __forceinline__ float gelu_exact(float x){
    return 0.5f * x * (1.0f + erff(x * 0.70710678118654752440f));
}
__device__ __forceinline__ unsigned int umin_(unsigned int a, unsigned int b){ return a < b ? a : b; }
__device__ __forceinline__ unsigned int umax_(unsigned int a, unsigned int b){ return a < b ? b : a; }
__device__ __forceinline__ unsigned short bf16rnd(float v){
    unsigned int bits = __builtin_bit_cast(unsigned int, v);
    return (unsigned short)((bits + 0x7fff + ((bits >> 16) & 1)) >> 16);
}

// ---------------- fc1 with f64 accumulation -> f64 t1 -------------------------------------------
__global__ __launch_bounds__(256) void k_fc1_f64(
    const float* __restrict__ in, const float* __restrict__ W, double* __restrict__ outd)
{
    constexpr int OT = 8, NT = 4;
    __shared__ float wtT[CH][OT];
    const int tid = threadIdx.x;
    const int o0  = blockIdx.y * OT;
    const int b   = blockIdx.z;
    const int n   = blockIdx.x * (256 * NT) + tid * NT;

    for (int lin = tid; lin < CH * OT; lin += 256){
        int c = lin >> 3, o = lin & 7;
        wtT[c][o] = W[(size_t)(o0 + o) * CH + c];
    }
    __syncthreads();

    double acc[OT][NT] = {};
    const float* ip = in + (size_t)b * CH * NPT + n;
    for (int c = 0; c < CH; ++c){
        float4 x4 = *reinterpret_cast<const float4*>(ip + (size_t)c * NPT);
        double xv[NT] = {x4.x, x4.y, x4.z, x4.w};
        float4 w0 = *reinterpret_cast<const float4*>(&wtT[c][0]);
        float4 w1 = *reinterpret_cast<const float4*>(&wtT[c][4]);
        double wv[OT] = {w0.x, w0.y, w0.z, w0.w, w1.x, w1.y, w1.z, w1.w};
        #pragma unroll
        for (int oo = 0; oo < OT; ++oo)
            #pragma unroll
            for (int j = 0; j < NT; ++j)
                acc[oo][j] = fma(wv[oo], xv[j], acc[oo][j]);
    }

    #pragma unroll
    for (int oo = 0; oo < OT; ++oo){
        size_t off = ((size_t)b * CH + o0 + oo) * NPT + n;
        #pragma unroll
        for (int j = 0; j < 4; ++j) outd[off + j] = acc[oo][j];
    }
}

// ---------------- f64 BN0 stats: fp32 scale/shift + f64 scale -----------------------------------
__global__ __launch_bounds__(256) void k_stats_f64(
    const double* __restrict__ t, const float* __restrict__ gamma,
    const float* __restrict__ beta, float* __restrict__ scale,
    float* __restrict__ shift, double* __restrict__ scd)
{
    const int c = blockIdx.x, tid = threadIdx.x;
    double s = 0., s2 = 0.;
    for (int b = 0; b < BSZ; ++b){
        const double* p = t + ((size_t)b * CH + c) * NPT;
        for (int n = tid; n < NPT; n += 256){ double v = p[n]; s += v; s2 += v * v; }
    }
    __shared__ double rs[256], rs2[256];
    rs[tid] = s; rs2[tid] = s2; __syncthreads();
    for (int off = 128; off; off >>= 1){
        if (tid < off){ rs[tid] += rs[tid + off]; rs2[tid] += rs2[tid + off]; }
        __syncthreads();
    }
    if (tid == 0){
        const double invn = 1.0 / (BSZ * NPT);
        double mean = rs[0] * invn;
        double var  = rs2[0] * invn - mean * mean;
        double rstd = 1.0 / sqrt(var + 1e-5);
        double s_   = rstd * (double)gamma[c];
        scale[c] = (float)s_;
        shift[c] = (float)((double)beta[c] - mean * s_);
        scd[c]   = s_;
    }
}

// ---------------- fused: transpose+scale -> featT(f64), feat32, featP (MFMA-fragment bf16), sqv -
__global__ void k_feat(
    const double* __restrict__ t1d, const double* __restrict__ scd,
    double* __restrict__ featT, float* __restrict__ feat32,
    unsigned short* __restrict__ featP, float* __restrict__ sqv)
{
    __shared__ double tile[32][33];
    __shared__ float sqp[32][33];
    const int n0 = blockIdx.x * 32, b = blockIdx.y;
    const int tx = threadIdx.x, ty = threadIdx.y;
    const int tid = ty * 32 + tx;
    float part[4] = {0.f, 0.f, 0.f, 0.f};
    unsigned short* fpb = featP + (size_t)b * NPT * CH;

    for (int cc = 0; cc < CH / 32; ++cc){
        const int cbase = cc * 32;
        #pragma unroll
        for (int r = 0; r < 32; r += 8){
            int c = cbase + ty + r;
            tile[ty + r][tx] = t1d[((size_t)b * CH + c) * NPT + n0 + tx] * scd[c];
        }
        __syncthreads();
        #pragma unroll
        for (int r = 0; r < 32; r += 8){
            int n = n0 + ty + r;
            int c = cbase + tx;
            double v = tile[tx][ty + r];
            size_t o = ((size_t)b * NPT + n) * CH + c;
            featT[o] = v;
            float f = (float)v;
            feat32[o] = f;
            part[r >> 3] = fmaf(f, f, part[r >> 3]);
        }
        if (tid < 128){
            const int t_ = tid >> 6;
            const int l  = tid & 63;
            const int r_ = l & 15, g_ = l >> 4;
            const int nl = t_ * 16 + r_;
            short8 pk;
            #pragma unroll
            for (int e = 0; e < 8; ++e)
                pk[e] = (short)bf16rnd((float)tile[g_ * 8 + e][nl]);
            const int tP = blockIdx.x * 2 + t_;
            *reinterpret_cast<short8*>(fpb + (size_t)(tP * 6 + cc) * 512 + l * 8) = pk;
        }
        __syncthreads();
    }
    #pragma unroll
    for (int j = 0; j < 4; ++j) sqp[ty + 8 * j][tx] = part[j];
    __syncthreads();
    if (ty == 0){
        float s = 0.f;
        #pragma unroll 8
        for (int k = 0; k < 32; ++k) s += sqp[tx][k];
        sqv[b * NPT + n0 + tx] = s;
    }
}

// ---------------- MFMA kNN prefilter v10: lane-contiguous fragment loads ------------------------
__global__ __launch_bounds__(512, 4) void k_knn_mfma(
    const unsigned short* __restrict__ featP, const float* __restrict__ sqv,
    int* __restrict__ idxh)
{
    __shared__ unsigned int mlist[8][16][17];
    const int tid  = threadIdx.x;
    const int wv   = tid >> 6;
    const int lane = tid & 63;
    const int r = lane & 15, g = lane >> 4;
    const int b    = blockIdx.y;
    const int qt   = blockIdx.x >> 1;
    const int half = blockIdx.x & 1;
    const int qs = wv >> 1, mq = wv & 1;
    const int tq   = qt * 4 + qs;
    const int tm0  = half * 128 + mq * 64;
    const unsigned short* fp = featP + (size_t)b * NPT * CH;

    short8 bq0, bq1, bq2, bq3, bq4, bq5;
    {
        const unsigned short* qp = fp + (size_t)tq * 3072 + lane * 8;
        bq0 = *reinterpret_cast<const short8*>(qp);
        bq1 = *reinterpret_cast<const short8*>(qp + 512);
        bq2 = *reinterpret_cast<const short8*>(qp + 1024);
        bq3 = *reinterpret_cast<const short8*>(qp + 1536);
        bq4 = *reinterpret_cast<const short8*>(qp + 2048);
        bq5 = *reinterpret_cast<const short8*>(qp + 2560);
    }

    unsigned int Q[16];
    #pragma unroll
    for (int e = 0; e < 16; ++e) Q[e] = 0xFFFFFFFFu;

    const float* sq = sqv + b * NPT;
    const unsigned short* pa = fp + (size_t)tm0 * 3072 + lane * 8;

    for (int it = 0; it < 64; ++it){
        const unsigned short* p = pa + (size_t)it * 3072;
        short8 a0 = *reinterpret_cast<const short8*>(p);
        short8 a1 = *reinterpret_cast<const short8*>(p + 512);
        short8 a2 = *reinterpret_cast<const short8*>(p + 1024);
        short8 a3 = *reinterpret_cast<const short8*>(p + 1536);
        short8 a4 = *reinterpret_cast<const short8*>(p + 2048);
        short8 a5 = *reinterpret_cast<const short8*>(p + 2560);
        const int tm = tm0 + it;
        float4 s4 = *reinterpret_cast<const float4*>(sq + tm * 16 + 4 * g);

        f32x4 acc = {0.f, 0.f, 0.f, 0.f};
        acc = __builtin_amdgcn_mfma_f32_16x16x32_bf16(a0, bq0, acc, 0, 0, 0);
        acc = __builtin_amdgcn_mfma_f32_16x16x32_bf16(a1, bq1, acc, 0, 0, 0);
        acc = __builtin_amdgcn_mfma_f32_16x16x32_bf16(a2, bq2, acc, 0, 0, 0);
        acc = __builtin_amdgcn_mfma_f32_16x16x32_bf16(a3, bq3, acc, 0, 0, 0);
        acc = __builtin_amdgcn_mfma_f32_16x16x32_bf16(a4, bq4, acc, 0, 0, 0);
        acc = __builtin_amdgcn_mfma_f32_16x16x32_bf16(a5, bq5, acc, 0, 0, 0);

        const int m0 = tm * 16 + 4 * g;
        float sa[4] = {s4.x, s4.y, s4.z, s4.w};
        #pragma unroll
        for (int u = 0; u < 4; ++u){
            float d = fmaf(-2.0f, acc[u], sa[u]);
            int bb = __builtin_bit_cast(int, d);
            unsigned int uu = (unsigned int)(bb ^ ((bb >> 31) | 0x80000000));
            unsigned int k  = (uu & 0xFFFFF000u) | (unsigned int)(m0 + u);
            #pragma unroll
            for (int e = 0; e < 16; ++e){
                unsigned int qe = Q[e];
                Q[e] = umin_(k, qe);
                k    = umax_(k, qe);
            }
        }
    }

    #pragma unroll 1
    for (int rd = 0; rd < 16; ++rd){
        unsigned int v = Q[0];
        v = umin_(v, (unsigned int)__shfl_xor((int)v, 16));
        v = umin_(v, (unsigned int)__shfl_xor((int)v, 32));
        bool win = (Q[0] == v);
        if (win){
            #pragma unroll
            for (int e = 0; e < 15; ++e) Q[e] = Q[e + 1];
            Q[15] = 0xFFFFFFFFu;
        }
        if (g == 0) mlist[wv][r][rd] = v;
    }
    if (g == 0) mlist[wv][r][16] = 0xFFFFFFFFu;
    __syncthreads();

    if (tid < 64){
        const int qsub = tid >> 4, rr = tid & 15;
        int i0 = 0, i1 = 0;
        int* op = idxh + ((size_t)(b * NPT + qt * 64 + qsub * 16 + rr) * 2 + half) * KPH;
        for (int rd = 0; rd < KPH; ++rd){
            unsigned int k0 = mlist[qsub * 2][rr][i0];
            unsigned int k1 = mlist[qsub * 2 + 1][rr][i1];
            unsigned int mm = umin_(k0, k1);
            op[rd] = (int)(mm & 0xFFFu);
            i0 += (k0 == mm); i1 += (k1 == mm);
        }
    }
}

// ---------------- fused refine v2: ILP distance batch + fp32 top-16 + certified f64 fallback ----
// 4 queries/block (one wave each). Phase 1: all 40 per-lane partials with 120 independent loads.
// Phase 2: 40 independent shuffle-reduce chains. Phase 3: selection + borderline f64 fallback.
__global__ __launch_bounds__(256) void k_refine(
    const float* __restrict__ feat32, const double* __restrict__ featT,
    const int* __restrict__ idxh, int* __restrict__ idxf)
{
    const int q = blockIdx.x * 4 + (threadIdx.x >> 6);
    const int b = blockIdx.y;
    const int lane = threadIdx.x & 63;
    const int* cl = idxh + ((size_t)b * NPT + q) * KCAND;
    const float* qv = feat32 + ((size_t)b * NPT + q) * CH;
    float q0 = qv[lane], q1 = qv[lane + 64], q2 = qv[lane + 128];

    float pd[KCAND];
    int   cm[KCAND];
    #pragma unroll
    for (int t = 0; t < KCAND; ++t){
        int m = cl[t];
        cm[t] = m;
        const float* cv = feat32 + ((size_t)b * NPT + m) * CH;
        float d0 = cv[lane] - q0, d1 = cv[lane + 64] - q1, d2 = cv[lane + 128] - q2;
        pd[t] = fmaf(d0, d0, fmaf(d1, d1, d2 * d2));
    }

    float myd = INFINITY; int mym = 0x7fffffff;
    #pragma unroll
    for (int t = 0; t < KCAND; ++t){
        float d = pd[t];
        #pragma unroll
        for (int off = 32; off; off >>= 1) d += __shfl_xor(d, off);
        if (lane == t){ myd = d; mym = cm[t]; }
    }

    float d16 = 0.f;
    for (int r = 0; r < KNB; ++r){
        float bv = myd; int bi = mym;
        #pragma unroll
        for (int off = 32; off; off >>= 1){
            float ov = __shfl_xor(bv, off);
            int   oi = __shfl_xor(bi, off);
            if (ov < bv || (ov == bv && oi < bi)){ bv = ov; bi = oi; }
        }
        if (lane == 0) idxf[((size_t)b * NPT + q) * KNB + r] = bi;
        if (mym == bi){ myd = INFINITY; mym = 0x7fffffff; }
        d16 = bv;
    }
    float b17 = myd;
    #pragma unroll
    for (int off = 32; off; off >>= 1) b17 = fminf(b17, __shfl_xor(b17, off));
    int flag = (b17 - d16 < 1e-3f + 2e-4f * d16) ? 1 : 0;
    flag = __shfl(flag, 0);
    if (!flag) return;

    // exact f64 re-rank (rare; wave-level divergence only)
    const double* qvd = featT + ((size_t)b * NPT + q) * CH;
    double Q0 = qvd[lane], Q1 = qvd[lane + 64], Q2 = qvd[lane + 128];
    double mydd = INFINITY; int mymd = 0x7fffffff;
    for (int t = 0; t < KCAND; ++t){
        int m = cm[t];
        const double* cv = featT + ((size_t)b * NPT + m) * CH;
        double d0 = cv[lane] - Q0, d1 = cv[lane + 64] - Q1, d2 = cv[lane + 128] - Q2;
        double d = d0 * d0 + d1 * d1 + d2 * d2;
        #pragma unroll
        for (int off = 32; off; off >>= 1) d += __shfl_xor(d, off);
        if (lane == t){ mydd = d; mymd = m; }
    }
    for (int r = 0; r < KNB; ++r){
        double bv = mydd; int bi = mymd;
        #pragma unroll
        for (int off = 32; off; off >>= 1){
            double ov = __shfl_xor(bv, off);
            int    oi = __shfl_xor(bi, off);
            if (ov < bv || (ov == bv && oi < bi)){ bv = ov; bi = oi; }
        }
        if (lane == 0) idxf[((size_t)b * NPT + q) * KNB + r] = bi;
        if (mymd == bi){ mydd = INFINITY; mymd = 0x7fffffff; }
    }
}

// ---------------- gather v2: coalesced rows + LDS-transposed hcat write -------------------------
__global__ __launch_bounds__(128) void k_gather2(
    const float* __restrict__ feat32, const float* __restrict__ sh0,
    const int* __restrict__ idx, float* __restrict__ hcat)
{
    __shared__ float lt[192 * 33];
    __shared__ int il[32 * KNB];
    const int tid = threadIdx.x;
    const int n0  = blockIdx.x * 32;
    const int cg  = blockIdx.y;
    const int b   = blockIdx.z;

    for (int i = tid; i < 32 * KNB; i += 128)
        il[i] = idx[((size_t)b * NPT + n0) * KNB + i];
    __syncthreads();

    const int nl = tid >> 2, sub = tid & 3;
    const int n  = n0 + nl;
    const float* fbase = feat32 + (size_t)b * NPT * CH;
    const float* qr = fbase + (size_t)n * CH + cg * 96;

    float4 qv[6], mx[6];
    #pragma unroll
    for (int j = 0; j < 6; ++j){
        qv[j] = *reinterpret_cast<const float4*>(qr + (sub + 4 * j) * 4);
        mx[j] = make_float4(-INFINITY, -INFINITY, -INFINITY, -INFINITY);
    }

    #pragma unroll 4
    for (int k = 0; k < KNB; ++k){
        const float* cr = fbase + (size_t)il[nl * KNB + k] * CH + cg * 96;
        #pragma unroll
        for (int j = 0; j < 6; ++j){
            float4 v = *reinterpret_cast<const float4*>(cr + (sub + 4 * j) * 4);
            mx[j].x = fmaxf(mx[j].x, v.x - qv[j].x);
            mx[j].y = fmaxf(mx[j].y, v.y - qv[j].y);
            mx[j].z = fmaxf(mx[j].z, v.z - qv[j].z);
            mx[j].w = fmaxf(mx[j].w, v.w - qv[j].w);
        }
    }

    #pragma unroll
    for (int j = 0; j < 6; ++j){
        const int cb = (sub + 4 * j) * 4;
        float4 s4 = *reinterpret_cast<const float4*>(sh0 + cg * 96 + cb);
        float fi[4] = {qv[j].x + s4.x, qv[j].y + s4.y, qv[j].z + s4.z, qv[j].w + s4.w};
        float mm[4] = {mx[j].x, mx[j].y, mx[j].z, mx[j].w};
        #pragma unroll
        for (int e = 0; e < 4; ++e){
            int cl = cb + e;
            lt[(2 * cl) * 33 + nl]     = fi[e];
            lt[(2 * cl + 1) * 33 + nl] = mm[e];
        }
    }
    __syncthreads();

    const int rsub = tid >> 5;
    const int ni   = tid & 31;
    for (int r0 = 0; r0 < 192; r0 += 4){
        int row = r0 + rsub;
        int ch  = cg * 192 + row;
        hcat[((size_t)b * 2 * CH + ch) * NPT + n0 + ni] = lt[row * 33 + ni];
    }
}

// ---------------- mr-conv GEMM (K=384) + bias, with fused BN1-stat atomics ----------------------
__global__ __launch_bounds__(256) void k_gemm_mr(
    const float* __restrict__ in, const float* __restrict__ W, const float* __restrict__ bias,
    float* __restrict__ out, float* __restrict__ s1sum, float* __restrict__ s1sq)
{
    constexpr int KDIM = 2 * CH, OT = 8, NT = 4;
    __shared__ float wtT[KDIM][OT];
    __shared__ float redS[4][8], redQ[4][8];
    const int tid = threadIdx.x;
    const int o0  = blockIdx.y * OT;
    const int b   = blockIdx.z;
    const int n   = blockIdx.x * (256 * NT) + tid * NT;

    for (int lin = tid; lin < KDIM * OT; lin += 256){
        int c = lin >> 3, o = lin & 7;
        wtT[c][o] = W[(size_t)(o0 + o) * KDIM + c];
    }
    __syncthreads();

    float acc[OT][NT] = {};
    const float* ip = in + (size_t)b * KDIM * NPT + n;
    #pragma unroll 2
    for (int c = 0; c < KDIM; ++c){
        float4 x4 = *reinterpret_cast<const float4*>(ip + (size_t)c * NPT);
        float xv[NT] = {x4.x, x4.y, x4.z, x4.w};
        float4 w0 = *reinterpret_cast<const float4*>(&wtT[c][0]);
        float4 w1 = *reinterpret_cast<const float4*>(&wtT[c][4]);
        float wv[OT] = {w0.x, w0.y, w0.z, w0.w, w1.x, w1.y, w1.z, w1.w};
        #pragma unroll
        for (int oo = 0; oo < OT; ++oo)
            #pragma unroll
            for (int j = 0; j < NT; ++j)
                acc[oo][j] = fmaf(wv[oo], xv[j], acc[oo][j]);
    }

    float ps[OT], pq[OT];
    #pragma unroll
    for (int oo = 0; oo < OT; ++oo){
        size_t off = ((size_t)b * CH + o0 + oo) * NPT + n;
        float add = bias[o0 + oo];
        float vals[4];
        float s = 0.f, q = 0.f;
        #pragma unroll
        for (int j = 0; j < 4; ++j){
            vals[j] = acc[oo][j] + add;
            s += vals[j];
            q = fmaf(vals[j], vals[j], q);
        }
        ps[oo] = s; pq[oo] = q;
        float4 o4; o4.x = vals[0]; o4.y = vals[1]; o4.z = vals[2]; o4.w = vals[3];
        *reinterpret_cast<float4*>(out + off) = o4;
    }

    #pragma unroll
    for (int oo = 0; oo < OT; ++oo){
        #pragma unroll
        for (int off = 32; off; off >>= 1){
            ps[oo] += __shfl_xor(ps[oo], off);
            pq[oo] += __shfl_xor(pq[oo], off);
        }
    }
    const int wv = tid >> 6, lane = tid & 63;
    if (lane == 0){
        #pragma unroll
        for (int oo = 0; oo < OT; ++oo){ redS[wv][oo] = ps[oo]; redQ[wv][oo] = pq[oo]; }
    }
    __syncthreads();
    if (tid < 8){
        float s = redS[0][tid] + redS[1][tid] + redS[2][tid] + redS[3][tid];
        float q = redQ[0][tid] + redQ[1][tid] + redQ[2][tid] + redQ[3][tid];
        atomicAdd(&s1sum[o0 + tid], s);
        atomicAdd(&s1sq[o0 + tid], q);
    }
}

// ---------------- u = gelu(gelu(BN1(t2))), BN1 from sums; fused BN2-stat atomics ----------------
__global__ __launch_bounds__(256) void k_u(
    const float* __restrict__ in, const float* __restrict__ s1sum, const float* __restrict__ s1sq,
    const float* __restrict__ gm, const float* __restrict__ bm,
    float* __restrict__ out, float* __restrict__ s2sum, float* __restrict__ s2sq)
{
    __shared__ float redS[4], redQ[4];
    const int c = blockIdx.y, b = blockIdx.z;
    const int n = (blockIdx.x * 256 + threadIdx.x) * 4;
    const float invn = 1.0f / NTOT;
    float mean = s1sum[c] * invn;
    float var  = s1sq[c] * invn - mean * mean;
    float rstd = rsqrtf(var + 1e-5f);
    float s = rstd * gm[c], t = bm[c] - mean * s;

    size_t i = ((size_t)b * CH + c) * NPT + n;
    float4 v = *reinterpret_cast<const float4*>(in + i);
    float4 o;
    o.x = gelu_exact(gelu_exact(fmaf(v.x, s, t)));
    o.y = gelu_exact(gelu_exact(fmaf(v.y, s, t)));
    o.z = gelu_exact(gelu_exact(fmaf(v.z, s, t)));
    o.w = gelu_exact(gelu_exact(fmaf(v.w, s, t)));
    *reinterpret_cast<float4*>(out + i) = o;

    float ps = o.x + o.y + o.z + o.w;
    float pq = fmaf(o.x, o.x, fmaf(o.y, o.y, fmaf(o.z, o.z, o.w * o.w)));
    #pragma unroll
    for (int off = 32; off; off >>= 1){
        ps += __shfl_xor(ps, off);
        pq += __shfl_xor(pq, off);
    }
    const int wv = threadIdx.x >> 6, lane = threadIdx.x & 63;
    if (lane == 0){ redS[wv] = ps; redQ[wv] = pq; }
    __syncthreads();
    if (threadIdx.x == 0){
        atomicAdd(&s2sum[c], redS[0] + redS[1] + redS[2] + redS[3]);
        atomicAdd(&s2sq[c],  redQ[0] + redQ[1] + redQ[2] + redQ[3]);
    }
}

// ---------------- fc2 GEMM with BN2 (from sums) folded into input + residual --------------------
__global__ __launch_bounds__(256) void k_gemm_fc2(
    const float* __restrict__ in, const float* __restrict__ W,
    const float* __restrict__ s2sum, const float* __restrict__ s2sq,
    const float* __restrict__ g1, const float* __restrict__ b1,
    const float* __restrict__ resid, float* __restrict__ out)
{
    constexpr int KDIM = CH, OT = 8, NT = 4;
    __shared__ float wtT[KDIM][OT];
    __shared__ float scl[KDIM], shl[KDIM];
    const int tid = threadIdx.x;
    const int o0  = blockIdx.y * OT;
    const int b   = blockIdx.z;
    const int n   = blockIdx.x * (256 * NT) + tid * NT;

    for (int lin = tid; lin < KDIM * OT; lin += 256){
        int c = lin >> 3, o = lin & 7;
        wtT[c][o] = W[(size_t)(o0 + o) * KDIM + c];
    }
    const float invn = 1.0f / NTOT;
    for (int c = tid; c < KDIM; c += 256){
        float mean = s2sum[c] * invn;
        float var  = s2sq[c] * invn - mean * mean;
        float rstd = rsqrtf(var + 1e-5f);
        float s = rstd * g1[c];
        scl[c] = s;
        shl[c] = b1[c] - mean * s;
    }
    __syncthreads();

    float acc[OT][NT] = {};
    const float* ip = in + (size_t)b * KDIM * NPT + n;
    #pragma unroll 2
    for (int c = 0; c < KDIM; ++c){
        float4 x4 = *reinterpret_cast<const float4*>(ip + (size_t)c * NPT);
        float xv[NT];
        xv[0] = fmaf(x4.x, scl[c], shl[c]);
        xv[1] = fmaf(x4.y, scl[c], shl[c]);
        xv[2] = fmaf(x4.z, scl[c], shl[c]);
        xv[3] = fmaf(x4.w, scl[c], shl[c]);
        float4 w0 = *reinterpret_cast<const float4*>(&wtT[c][0]);
        float4 w1 = *reinterpret_cast<const float4*>(&wtT[c][4]);
        float wv[OT] = {w0.x, w0.y, w0.z, w0.w, w1.x, w1.y, w1.z, w1.w};
        #pragma unroll
        for (int oo = 0; oo < OT; ++oo)
            #pragma unroll
            for (int j = 0; j < NT; ++j)
                acc[oo][j] = fmaf(wv[oo], xv[j], acc[oo][j]);
    }

    #pragma unroll
    for (int oo = 0; oo < OT; ++oo){
        size_t off = ((size_t)b * CH + o0 + oo) * NPT + n;
        float4 r4 = *reinterpret_cast<const float4*>(resid + off);
        float4 o4;
        o4.x = acc[oo][0] + r4.x; o4.y = acc[oo][1] + r4.y;
        o4.z = acc[oo][2] + r4.z; o4.w = acc[oo][3] + r4.w;
        *reinterpret_cast<float4*>(out + off) = o4;
    }
}

extern "C" void kernel_launch(void* const* d_in, const int* in_sizes, int n_in,
                              void* d_out, int out_size, void* d_ws, size_t ws_size,
                              hipStream_t stream)
{
    const float* x    = (const float*)d_in[0];
    const float* w1   = (const float*)d_in[1];
    const float* w2   = (const float*)d_in[2];
    const float* wmr  = (const float*)d_in[3];
    const float* bmr  = (const float*)d_in[4];
    const float* g0   = (const float*)d_in[5];
    const float* b0   = (const float*)d_in[6];
    const float* gm   = (const float*)d_in[7];
    const float* bm   = (const float*)d_in[8];
    const float* g1   = (const float*)d_in[9];
    const float* b1   = (const float*)d_in[10];
    float* outp = (float*)d_out;

    const size_t BCN = (size_t)BSZ * CH * NPT;
    float*  A      = (float*)d_ws;                       // BCN f32: t2
    float*  Bb     = A + BCN;                            // BCN f32: featP (bf16) -> u
    unsigned short* featP = (unsigned short*)Bb;
    float*  Cc     = Bb + BCN;                           // 2*BCN f32: t1d (f64) -> hcat
    double* t1d    = (double*)Cc;
    double* featT  = (double*)(Cc + 2 * BCN);            // BCN f64
    float*  feat32 = (float*)(featT + BCN);              // BCN f32
    float*  sqv    = feat32 + BCN;                       // B*N
    int*    idxh   = (int*)(sqv + (size_t)BSZ * NPT);    // B*N*40
    int*    idxf   = idxh + (size_t)BSZ * NPT * KCAND;   // B*N*16
    float*  bnacc  = (float*)(idxf + (size_t)BSZ * NPT * KNB);  // 4*CH f32
    float *s1sum = bnacc, *s1sq = bnacc + CH, *s2sum = bnacc + 2 * CH, *s2sq = bnacc + 3 * CH;
    double* scd    = (double*)(bnacc + 4 * CH);
    float*  scb    = (float*)(scd + CH);
    float *sc0 = scb, *sh0 = scb + CH;

    dim3 gg(NPT / 1024, CH / 8, BSZ);
    dim3 ge(NPT / 1024, CH, BSZ);

    hipMemsetAsync(bnacc, 0, 4 * CH * sizeof(float), stream);
    // fc1 (f64 accumulate)
    k_fc1_f64<<<gg, 256, 0, stream>>>(x, w1, t1d);
    // BN0 stats in f64
    k_stats_f64<<<CH, 256, 0, stream>>>(t1d, g0, b0, sc0, sh0, scd);
    // fused transpose/scale -> featT + feat32 + featP(fragment layout) + sqv
    k_feat<<<dim3(NPT / 32, BSZ), dim3(32, 8), 0, stream>>>(t1d, scd, featT, feat32, featP, sqv);
    // kNN prefilter (lane-contiguous fragment loads)
    k_knn_mfma<<<dim3(2 * NPT / 64, BSZ), 512, 0, stream>>>(featP, sqv, idxh);
    // fused refine v2 (ILP distances + fp32 top-16 + certified f64 fallback)
    k_refine<<<dim3(NPT / 4, BSZ), 256, 0, stream>>>(feat32, featT, idxh, idxf);
    // gather (coalesced; writes hcat over dead t1d)
    k_gather2<<<dim3(NPT / 32, 2, BSZ), 128, 0, stream>>>(feat32, sh0, idxf, Cc);
    // mr conv + bias + BN1-stat atomics
    k_gemm_mr<<<gg, 256, 0, stream>>>(Cc, wmr, bmr, A, s1sum, s1sq);
    // u = gelu(gelu(BN1(t2))) + BN2-stat atomics
    k_u<<<ge, 256, 0, stream>>>(A, s1sum, s1sq, gm, bm, Bb, s2sum, s2sq);
    // fc2 with BN2 folded + residual
    k_gemm_fc2<<<gg, 256, 0, stream>>>(Bb, w2, s2sum, s2sq, g1, b1, x, outp);
}

// Round 15
// 482.681 us; speedup vs baseline: 1.0527x; 1.0527x over previous
//
#include <hip/hip_runtime.h>
#include <hip/hip_bf16.h>
#include <math.h>

#define BSZ 4
#define NPT 4096
#define CH  192
#define KNB 16
#define KPH 20              // kept per half
#define KCAND (2 * KPH)     // refine candidates
#define NTOT ((float)(BSZ * NPT))

typedef short short8 __attribute__((ext_vector_type(8)));
typedef float f32x4  __attribute__((ext_vector_type(4)));

__device__ __forceinline__ float gelu_exact(float x){
    return 0.5f * x * (1.0f + erff(x * 0.70710678118654752440f));
}
__device__ __forceinline__ unsigned int umin_(unsigned int a, unsigned int b){ return a < b ? a : b; }
__device__ __forceinline__ unsigned int umax_(unsigned int a, unsigned int b){ return a < b ? b : a; }
__device__ __forceinline__ unsigned short bf16rnd(float v){
    unsigned int bits = __builtin_bit_cast(unsigned int, v);
    return (unsigned short)((bits + 0x7fff + ((bits >> 16) & 1)) >> 16);
}

// ---------------- fc1 with f64 accumulation -> f64 t1 -------------------------------------------
__global__ __launch_bounds__(256) void k_fc1_f64(
    const float* __restrict__ in, const float* __restrict__ W, double* __restrict__ outd)
{
    constexpr int OT = 8, NT = 4;
    __shared__ float wtT[CH][OT];
    const int tid = threadIdx.x;
    const int o0  = blockIdx.y * OT;
    const int b   = blockIdx.z;
    const int n   = blockIdx.x * (256 * NT) + tid * NT;

    for (int lin = tid; lin < CH * OT; lin += 256){
        int c = lin >> 3, o = lin & 7;
        wtT[c][o] = W[(size_t)(o0 + o) * CH + c];
    }
    __syncthreads();

    double acc[OT][NT] = {};
    const float* ip = in + (size_t)b * CH * NPT + n;
    for (int c = 0; c < CH; ++c){
        float4 x4 = *reinterpret_cast<const float4*>(ip + (size_t)c * NPT);
        double xv[NT] = {x4.x, x4.y, x4.z, x4.w};
        float4 w0 = *reinterpret_cast<const float4*>(&wtT[c][0]);
        float4 w1 = *reinterpret_cast<const float4*>(&wtT[c][4]);
        double wv[OT] = {w0.x, w0.y, w0.z, w0.w, w1.x, w1.y, w1.z, w1.w};
        #pragma unroll
        for (int oo = 0; oo < OT; ++oo)
            #pragma unroll
            for (int j = 0; j < NT; ++j)
                acc[oo][j] = fma(wv[oo], xv[j], acc[oo][j]);
    }

    #pragma unroll
    for (int oo = 0; oo < OT; ++oo){
        size_t off = ((size_t)b * CH + o0 + oo) * NPT + n;
        #pragma unroll
        for (int j = 0; j < 4; ++j) outd[off + j] = acc[oo][j];
    }
}

// ---------------- f64 BN0 stats: fp32 scale/shift + f64 scale -----------------------------------
__global__ __launch_bounds__(256) void k_stats_f64(
    const double* __restrict__ t, const float* __restrict__ gamma,
    const float* __restrict__ beta, float* __restrict__ scale,
    float* __restrict__ shift, double* __restrict__ scd)
{
    const int c = blockIdx.x, tid = threadIdx.x;
    double s = 0., s2 = 0.;
    for (int b = 0; b < BSZ; ++b){
        const double* p = t + ((size_t)b * CH + c) * NPT;
        for (int n = tid; n < NPT; n += 256){ double v = p[n]; s += v; s2 += v * v; }
    }
    __shared__ double rs[256], rs2[256];
    rs[tid] = s; rs2[tid] = s2; __syncthreads();
    for (int off = 128; off; off >>= 1){
        if (tid < off){ rs[tid] += rs[tid + off]; rs2[tid] += rs2[tid + off]; }
        __syncthreads();
    }
    if (tid == 0){
        const double invn = 1.0 / (BSZ * NPT);
        double mean = rs[0] * invn;
        double var  = rs2[0] * invn - mean * mean;
        double rstd = 1.0 / sqrt(var + 1e-5);
        double s_   = rstd * (double)gamma[c];
        scale[c] = (float)s_;
        shift[c] = (float)((double)beta[c] - mean * s_);
        scd[c]   = s_;
    }
}

// ---------------- fused: transpose+scale -> featT(f64), feat32, featP (MFMA-fragment bf16), sqv -
__global__ void k_feat(
    const double* __restrict__ t1d, const double* __restrict__ scd,
    double* __restrict__ featT, float* __restrict__ feat32,
    unsigned short* __restrict__ featP, float* __restrict__ sqv)
{
    __shared__ double tile[32][33];
    __shared__ float sqp[32][33];
    const int n0 = blockIdx.x * 32, b = blockIdx.y;
    const int tx = threadIdx.x, ty = threadIdx.y;
    const int tid = ty * 32 + tx;
    float part[4] = {0.f, 0.f, 0.f, 0.f};
    unsigned short* fpb = featP + (size_t)b * NPT * CH;

    for (int cc = 0; cc < CH / 32; ++cc){
        const int cbase = cc * 32;
        #pragma unroll
        for (int r = 0; r < 32; r += 8){
            int c = cbase + ty + r;
            tile[ty + r][tx] = t1d[((size_t)b * CH + c) * NPT + n0 + tx] * scd[c];
        }
        __syncthreads();
        #pragma unroll
        for (int r = 0; r < 32; r += 8){
            int n = n0 + ty + r;
            int c = cbase + tx;
            double v = tile[tx][ty + r];
            size_t o = ((size_t)b * NPT + n) * CH + c;
            featT[o] = v;
            float f = (float)v;
            feat32[o] = f;
            part[r >> 3] = fmaf(f, f, part[r >> 3]);
        }
        if (tid < 128){
            const int t_ = tid >> 6;
            const int l  = tid & 63;
            const int r_ = l & 15, g_ = l >> 4;
            const int nl = t_ * 16 + r_;
            short8 pk;
            #pragma unroll
            for (int e = 0; e < 8; ++e)
                pk[e] = (short)bf16rnd((float)tile[g_ * 8 + e][nl]);
            const int tP = blockIdx.x * 2 + t_;
            *reinterpret_cast<short8*>(fpb + (size_t)(tP * 6 + cc) * 512 + l * 8) = pk;
        }
        __syncthreads();
    }
    #pragma unroll
    for (int j = 0; j < 4; ++j) sqp[ty + 8 * j][tx] = part[j];
    __syncthreads();
    if (ty == 0){
        float s = 0.f;
        #pragma unroll 8
        for (int k = 0; k < 32; ++k) s += sqp[tx][k];
        sqv[b * NPT + n0 + tx] = s;
    }
}

// ---------------- MFMA kNN prefilter v10: lane-contiguous fragment loads ------------------------
__global__ __launch_bounds__(512, 4) void k_knn_mfma(
    const unsigned short* __restrict__ featP, const float* __restrict__ sqv,
    int* __restrict__ idxh)
{
    __shared__ unsigned int mlist[8][16][17];
    const int tid  = threadIdx.x;
    const int wv   = tid >> 6;
    const int lane = tid & 63;
    const int r = lane & 15, g = lane >> 4;
    const int b    = blockIdx.y;
    const int qt   = blockIdx.x >> 1;
    const int half = blockIdx.x & 1;
    const int qs = wv >> 1, mq = wv & 1;
    const int tq   = qt * 4 + qs;
    const int tm0  = half * 128 + mq * 64;
    const unsigned short* fp = featP + (size_t)b * NPT * CH;

    short8 bq0, bq1, bq2, bq3, bq4, bq5;
    {
        const unsigned short* qp = fp + (size_t)tq * 3072 + lane * 8;
        bq0 = *reinterpret_cast<const short8*>(qp);
        bq1 = *reinterpret_cast<const short8*>(qp + 512);
        bq2 = *reinterpret_cast<const short8*>(qp + 1024);
        bq3 = *reinterpret_cast<const short8*>(qp + 1536);
        bq4 = *reinterpret_cast<const short8*>(qp + 2048);
        bq5 = *reinterpret_cast<const short8*>(qp + 2560);
    }

    unsigned int Q[16];
    #pragma unroll
    for (int e = 0; e < 16; ++e) Q[e] = 0xFFFFFFFFu;

    const float* sq = sqv + b * NPT;
    const unsigned short* pa = fp + (size_t)tm0 * 3072 + lane * 8;

    for (int it = 0; it < 64; ++it){
        const unsigned short* p = pa + (size_t)it * 3072;
        short8 a0 = *reinterpret_cast<const short8*>(p);
        short8 a1 = *reinterpret_cast<const short8*>(p + 512);
        short8 a2 = *reinterpret_cast<const short8*>(p + 1024);
        short8 a3 = *reinterpret_cast<const short8*>(p + 1536);
        short8 a4 = *reinterpret_cast<const short8*>(p + 2048);
        short8 a5 = *reinterpret_cast<const short8*>(p + 2560);
        const int tm = tm0 + it;
        float4 s4 = *reinterpret_cast<const float4*>(sq + tm * 16 + 4 * g);

        f32x4 acc = {0.f, 0.f, 0.f, 0.f};
        acc = __builtin_amdgcn_mfma_f32_16x16x32_bf16(a0, bq0, acc, 0, 0, 0);
        acc = __builtin_amdgcn_mfma_f32_16x16x32_bf16(a1, bq1, acc, 0, 0, 0);
        acc = __builtin_amdgcn_mfma_f32_16x16x32_bf16(a2, bq2, acc, 0, 0, 0);
        acc = __builtin_amdgcn_mfma_f32_16x16x32_bf16(a3, bq3, acc, 0, 0, 0);
        acc = __builtin_amdgcn_mfma_f32_16x16x32_bf16(a4, bq4, acc, 0, 0, 0);
        acc = __builtin_amdgcn_mfma_f32_16x16x32_bf16(a5, bq5, acc, 0, 0, 0);

        const int m0 = tm * 16 + 4 * g;
        float sa[4] = {s4.x, s4.y, s4.z, s4.w};
        #pragma unroll
        for (int u = 0; u < 4; ++u){
            float d = fmaf(-2.0f, acc[u], sa[u]);
            int bb = __builtin_bit_cast(int, d);
            unsigned int uu = (unsigned int)(bb ^ ((bb >> 31) | 0x80000000));
            unsigned int k  = (uu & 0xFFFFF000u) | (unsigned int)(m0 + u);
            #pragma unroll
            for (int e = 0; e < 16; ++e){
                unsigned int qe = Q[e];
                Q[e] = umin_(k, qe);
                k    = umax_(k, qe);
            }
        }
    }

    #pragma unroll 1
    for (int rd = 0; rd < 16; ++rd){
        unsigned int v = Q[0];
        v = umin_(v, (unsigned int)__shfl_xor((int)v, 16));
        v = umin_(v, (unsigned int)__shfl_xor((int)v, 32));
        bool win = (Q[0] == v);
        if (win){
            #pragma unroll
            for (int e = 0; e < 15; ++e) Q[e] = Q[e + 1];
            Q[15] = 0xFFFFFFFFu;
        }
        if (g == 0) mlist[wv][r][rd] = v;
    }
    if (g == 0) mlist[wv][r][16] = 0xFFFFFFFFu;
    __syncthreads();

    if (tid < 64){
        const int qsub = tid >> 4, rr = tid & 15;
        int i0 = 0, i1 = 0;
        int* op = idxh + ((size_t)(b * NPT + qt * 64 + qsub * 16 + rr) * 2 + half) * KPH;
        for (int rd = 0; rd < KPH; ++rd){
            unsigned int k0 = mlist[qsub * 2][rr][i0];
            unsigned int k1 = mlist[qsub * 2 + 1][rr][i1];
            unsigned int mm = umin_(k0, k1);
            op[rd] = (int)(mm & 0xFFFu);
            i0 += (k0 == mm); i1 += (k1 == mm);
        }
    }
}

// ---------------- fused refine v3: chunked-ILP distances (no spill) + certified f64 fallback ----
// 4 queries/block (one wave each). Chunks of 8 candidates: 24 independent loads in flight,
// then 8 independent reduce chains. pd[8]+cm[8] = 16 regs -> no scratch.
__global__ __launch_bounds__(256) void k_refine(
    const float* __restrict__ feat32, const double* __restrict__ featT,
    const int* __restrict__ idxh, int* __restrict__ idxf)
{
    const int q = blockIdx.x * 4 + (threadIdx.x >> 6);
    const int b = blockIdx.y;
    const int lane = threadIdx.x & 63;
    const int* cl = idxh + ((size_t)b * NPT + q) * KCAND;
    const float* qv = feat32 + ((size_t)b * NPT + q) * CH;
    float q0 = qv[lane], q1 = qv[lane + 64], q2 = qv[lane + 128];

    float myd = INFINITY; int mym = 0x7fffffff;
    #pragma unroll
    for (int t0 = 0; t0 < KCAND; t0 += 8){
        float pd[8]; int cm[8];
        #pragma unroll
        for (int j = 0; j < 8; ++j){
            int m = cl[t0 + j];
            cm[j] = m;
            const float* cv = feat32 + ((size_t)b * NPT + m) * CH;
            float d0 = cv[lane] - q0, d1 = cv[lane + 64] - q1, d2 = cv[lane + 128] - q2;
            pd[j] = fmaf(d0, d0, fmaf(d1, d1, d2 * d2));
        }
        #pragma unroll
        for (int j = 0; j < 8; ++j){
            float d = pd[j];
            #pragma unroll
            for (int off = 32; off; off >>= 1) d += __shfl_xor(d, off);
            if (lane == t0 + j){ myd = d; mym = cm[j]; }
        }
    }

    float d16 = 0.f;
    for (int r = 0; r < KNB; ++r){
        float bv = myd; int bi = mym;
        #pragma unroll
        for (int off = 32; off; off >>= 1){
            float ov = __shfl_xor(bv, off);
            int   oi = __shfl_xor(bi, off);
            if (ov < bv || (ov == bv && oi < bi)){ bv = ov; bi = oi; }
        }
        if (lane == 0) idxf[((size_t)b * NPT + q) * KNB + r] = bi;
        if (mym == bi){ myd = INFINITY; mym = 0x7fffffff; }
        d16 = bv;
    }
    float b17 = myd;
    #pragma unroll
    for (int off = 32; off; off >>= 1) b17 = fminf(b17, __shfl_xor(b17, off));
    int flag = (b17 - d16 < 1e-3f + 2e-4f * d16) ? 1 : 0;
    flag = __shfl(flag, 0);
    if (!flag) return;

    // exact f64 re-rank (rare; wave-level divergence only)
    const double* qvd = featT + ((size_t)b * NPT + q) * CH;
    double Q0 = qvd[lane], Q1 = qvd[lane + 64], Q2 = qvd[lane + 128];
    double mydd = INFINITY; int mymd = 0x7fffffff;
    for (int t = 0; t < KCAND; ++t){
        int m = cl[t];
        const double* cv = featT + ((size_t)b * NPT + m) * CH;
        double d0 = cv[lane] - Q0, d1 = cv[lane + 64] - Q1, d2 = cv[lane + 128] - Q2;
        double d = d0 * d0 + d1 * d1 + d2 * d2;
        #pragma unroll
        for (int off = 32; off; off >>= 1) d += __shfl_xor(d, off);
        if (lane == t){ mydd = d; mymd = m; }
    }
    for (int r = 0; r < KNB; ++r){
        double bv = mydd; int bi = mymd;
        #pragma unroll
        for (int off = 32; off; off >>= 1){
            double ov = __shfl_xor(bv, off);
            int    oi = __shfl_xor(bi, off);
            if (ov < bv || (ov == bv && oi < bi)){ bv = ov; bi = oi; }
        }
        if (lane == 0) idxf[((size_t)b * NPT + q) * KNB + r] = bi;
        if (mymd == bi){ mydd = INFINITY; mymd = 0x7fffffff; }
    }
}

// ---------------- gather v2: coalesced rows + LDS-transposed hcat write -------------------------
__global__ __launch_bounds__(128) void k_gather2(
    const float* __restrict__ feat32, const float* __restrict__ sh0,
    const int* __restrict__ idx, float* __restrict__ hcat)
{
    __shared__ float lt[192 * 33];
    __shared__ int il[32 * KNB];
    const int tid = threadIdx.x;
    const int n0  = blockIdx.x * 32;
    const int cg  = blockIdx.y;
    const int b   = blockIdx.z;

    for (int i = tid; i < 32 * KNB; i += 128)
        il[i] = idx[((size_t)b * NPT + n0) * KNB + i];
    __syncthreads();

    const int nl = tid >> 2, sub = tid & 3;
    const int n  = n0 + nl;
    const float* fbase = feat32 + (size_t)b * NPT * CH;
    const float* qr = fbase + (size_t)n * CH + cg * 96;

    float4 qv[6], mx[6];
    #pragma unroll
    for (int j = 0; j < 6; ++j){
        qv[j] = *reinterpret_cast<const float4*>(qr + (sub + 4 * j) * 4);
        mx[j] = make_float4(-INFINITY, -INFINITY, -INFINITY, -INFINITY);
    }

    #pragma unroll 4
    for (int k = 0; k < KNB; ++k){
        const float* cr = fbase + (size_t)il[nl * KNB + k] * CH + cg * 96;
        #pragma unroll
        for (int j = 0; j < 6; ++j){
            float4 v = *reinterpret_cast<const float4*>(cr + (sub + 4 * j) * 4);
            mx[j].x = fmaxf(mx[j].x, v.x - qv[j].x);
            mx[j].y = fmaxf(mx[j].y, v.y - qv[j].y);
            mx[j].z = fmaxf(mx[j].z, v.z - qv[j].z);
            mx[j].w = fmaxf(mx[j].w, v.w - qv[j].w);
        }
    }

    #pragma unroll
    for (int j = 0; j < 6; ++j){
        const int cb = (sub + 4 * j) * 4;
        float4 s4 = *reinterpret_cast<const float4*>(sh0 + cg * 96 + cb);
        float fi[4] = {qv[j].x + s4.x, qv[j].y + s4.y, qv[j].z + s4.z, qv[j].w + s4.w};
        float mm[4] = {mx[j].x, mx[j].y, mx[j].z, mx[j].w};
        #pragma unroll
        for (int e = 0; e < 4; ++e){
            int cl = cb + e;
            lt[(2 * cl) * 33 + nl]     = fi[e];
            lt[(2 * cl + 1) * 33 + nl] = mm[e];
        }
    }
    __syncthreads();

    const int rsub = tid >> 5;
    const int ni   = tid & 31;
    for (int r0 = 0; r0 < 192; r0 += 4){
        int row = r0 + rsub;
        int ch  = cg * 192 + row;
        hcat[((size_t)b * 2 * CH + ch) * NPT + n0 + ni] = lt[row * 33 + ni];
    }
}

// ---------------- mr-conv GEMM (K=384) + bias, with fused BN1-stat atomics ----------------------
__global__ __launch_bounds__(256) void k_gemm_mr(
    const float* __restrict__ in, const float* __restrict__ W, const float* __restrict__ bias,
    float* __restrict__ out, float* __restrict__ s1sum, float* __restrict__ s1sq)
{
    constexpr int KDIM = 2 * CH, OT = 8, NT = 4;
    __shared__ float wtT[KDIM][OT];
    __shared__ float redS[4][8], redQ[4][8];
    const int tid = threadIdx.x;
    const int o0  = blockIdx.y * OT;
    const int b   = blockIdx.z;
    const int n   = blockIdx.x * (256 * NT) + tid * NT;

    for (int lin = tid; lin < KDIM * OT; lin += 256){
        int c = lin >> 3, o = lin & 7;
        wtT[c][o] = W[(size_t)(o0 + o) * KDIM + c];
    }
    __syncthreads();

    float acc[OT][NT] = {};
    const float* ip = in + (size_t)b * KDIM * NPT + n;
    #pragma unroll 2
    for (int c = 0; c < KDIM; ++c){
        float4 x4 = *reinterpret_cast<const float4*>(ip + (size_t)c * NPT);
        float xv[NT] = {x4.x, x4.y, x4.z, x4.w};
        float4 w0 = *reinterpret_cast<const float4*>(&wtT[c][0]);
        float4 w1 = *reinterpret_cast<const float4*>(&wtT[c][4]);
        float wv[OT] = {w0.x, w0.y, w0.z, w0.w, w1.x, w1.y, w1.z, w1.w};
        #pragma unroll
        for (int oo = 0; oo < OT; ++oo)
            #pragma unroll
            for (int j = 0; j < NT; ++j)
                acc[oo][j] = fmaf(wv[oo], xv[j], acc[oo][j]);
    }

    float ps[OT], pq[OT];
    #pragma unroll
    for (int oo = 0; oo < OT; ++oo){
        size_t off = ((size_t)b * CH + o0 + oo) * NPT + n;
        float add = bias[o0 + oo];
        float vals[4];
        float s = 0.f, q = 0.f;
        #pragma unroll
        for (int j = 0; j < 4; ++j){
            vals[j] = acc[oo][j] + add;
            s += vals[j];
            q = fmaf(vals[j], vals[j], q);
        }
        ps[oo] = s; pq[oo] = q;
        float4 o4; o4.x = vals[0]; o4.y = vals[1]; o4.z = vals[2]; o4.w = vals[3];
        *reinterpret_cast<float4*>(out + off) = o4;
    }

    #pragma unroll
    for (int oo = 0; oo < OT; ++oo){
        #pragma unroll
        for (int off = 32; off; off >>= 1){
            ps[oo] += __shfl_xor(ps[oo], off);
            pq[oo] += __shfl_xor(pq[oo], off);
        }
    }
    const int wv = tid >> 6, lane = tid & 63;
    if (lane == 0){
        #pragma unroll
        for (int oo = 0; oo < OT; ++oo){ redS[wv][oo] = ps[oo]; redQ[wv][oo] = pq[oo]; }
    }
    __syncthreads();
    if (tid < 8){
        float s = redS[0][tid] + redS[1][tid] + redS[2][tid] + redS[3][tid];
        float q = redQ[0][tid] + redQ[1][tid] + redQ[2][tid] + redQ[3][tid];
        atomicAdd(&s1sum[o0 + tid], s);
        atomicAdd(&s1sq[o0 + tid], q);
    }
}

// ---------------- u = gelu(gelu(BN1(t2))), BN1 from sums; fused BN2-stat atomics ----------------
__global__ __launch_bounds__(256) void k_u(
    const float* __restrict__ in, const float* __restrict__ s1sum, const float* __restrict__ s1sq,
    const float* __restrict__ gm, const float* __restrict__ bm,
    float* __restrict__ out, float* __restrict__ s2sum, float* __restrict__ s2sq)
{
    __shared__ float redS[4], redQ[4];
    const int c = blockIdx.y, b = blockIdx.z;
    const int n = (blockIdx.x * 256 + threadIdx.x) * 4;
    const float invn = 1.0f / NTOT;
    float mean = s1sum[c] * invn;
    float var  = s1sq[c] * invn - mean * mean;
    float rstd = rsqrtf(var + 1e-5f);
    float s = rstd * gm[c], t = bm[c] - mean * s;

    size_t i = ((size_t)b * CH + c) * NPT + n;
    float4 v = *reinterpret_cast<const float4*>(in + i);
    float4 o;
    o.x = gelu_exact(gelu_exact(fmaf(v.x, s, t)));
    o.y = gelu_exact(gelu_exact(fmaf(v.y, s, t)));
    o.z = gelu_exact(gelu_exact(fmaf(v.z, s, t)));
    o.w = gelu_exact(gelu_exact(fmaf(v.w, s, t)));
    *reinterpret_cast<float4*>(out + i) = o;

    float ps = o.x + o.y + o.z + o.w;
    float pq = fmaf(o.x, o.x, fmaf(o.y, o.y, fmaf(o.z, o.z, o.w * o.w)));
    #pragma unroll
    for (int off = 32; off; off >>= 1){
        ps += __shfl_xor(ps, off);
        pq += __shfl_xor(pq, off);
    }
    const int wv = threadIdx.x >> 6, lane = threadIdx.x & 63;
    if (lane == 0){ redS[wv] = ps; redQ[wv] = pq; }
    __syncthreads();
    if (threadIdx.x == 0){
        atomicAdd(&s2sum[c], redS[0] + redS[1] + redS[2] + redS[3]);
        atomicAdd(&s2sq[c],  redQ[0] + redQ[1] + redQ[2] + redQ[3]);
    }
}

// ---------------- fc2 GEMM with BN2 (from sums) folded into input + residual --------------------
__global__ __launch_bounds__(256) void k_gemm_fc2(
    const float* __restrict__ in, const float* __restrict__ W,
    const float* __restrict__ s2sum, const float* __restrict__ s2sq,
    const float* __restrict__ g1, const float* __restrict__ b1,
    const float* __restrict__ resid, float* __restrict__ out)
{
    constexpr int KDIM = CH, OT = 8, NT = 4;
    __shared__ float wtT[KDIM][OT];
    __shared__ float scl[KDIM], shl[KDIM];
    const int tid = threadIdx.x;
    const int o0  = blockIdx.y * OT;
    const int b   = blockIdx.z;
    const int n   = blockIdx.x * (256 * NT) + tid * NT;

    for (int lin = tid; lin < KDIM * OT; lin += 256){
        int c = lin >> 3, o = lin & 7;
        wtT[c][o] = W[(size_t)(o0 + o) * KDIM + c];
    }
    const float invn = 1.0f / NTOT;
    for (int c = tid; c < KDIM; c += 256){
        float mean = s2sum[c] * invn;
        float var  = s2sq[c] * invn - mean * mean;
        float rstd = rsqrtf(var + 1e-5f);
        float s = rstd * g1[c];
        scl[c] = s;
        shl[c] = b1[c] - mean * s;
    }
    __syncthreads();

    float acc[OT][NT] = {};
    const float* ip = in + (size_t)b * KDIM * NPT + n;
    #pragma unroll 2
    for (int c = 0; c < KDIM; ++c){
        float4 x4 = *reinterpret_cast<const float4*>(ip + (size_t)c * NPT);
        float xv[NT];
        xv[0] = fmaf(x4.x, scl[c], shl[c]);
        xv[1] = fmaf(x4.y, scl[c], shl[c]);
        xv[2] = fmaf(x4.z, scl[c], shl[c]);
        xv[3] = fmaf(x4.w, scl[c], shl[c]);
        float4 w0 = *reinterpret_cast<const float4*>(&wtT[c][0]);
        float4 w1 = *reinterpret_cast<const float4*>(&wtT[c][4]);
        float wv[OT] = {w0.x, w0.y, w0.z, w0.w, w1.x, w1.y, w1.z, w1.w};
        #pragma unroll
        for (int oo = 0; oo < OT; ++oo)
            #pragma unroll
            for (int j = 0; j < NT; ++j)
                acc[oo][j] = fmaf(wv[oo], xv[j], acc[oo][j]);
    }

    #pragma unroll
    for (int oo = 0; oo < OT; ++oo){
        size_t off = ((size_t)b * CH + o0 + oo) * NPT + n;
        float4 r4 = *reinterpret_cast<const float4*>(resid + off);
        float4 o4;
        o4.x = acc[oo][0] + r4.x; o4.y = acc[oo][1] + r4.y;
        o4.z = acc[oo][2] + r4.z; o4.w = acc[oo][3] + r4.w;
        *reinterpret_cast<float4*>(out + off) = o4;
    }
}

extern "C" void kernel_launch(void* const* d_in, const int* in_sizes, int n_in,
                              void* d_out, int out_size, void* d_ws, size_t ws_size,
                              hipStream_t stream)
{
    const float* x    = (const float*)d_in[0];
    const float* w1   = (const float*)d_in[1];
    const float* w2   = (const float*)d_in[2];
    const float* wmr  = (const float*)d_in[3];
    const float* bmr  = (const float*)d_in[4];
    const float* g0   = (const float*)d_in[5];
    const float* b0   = (const float*)d_in[6];
    const float* gm   = (const float*)d_in[7];
    const float* bm   = (const float*)d_in[8];
    const float* g1   = (const float*)d_in[9];
    const float* b1   = (const float*)d_in[10];
    float* outp = (float*)d_out;

    const size_t BCN = (size_t)BSZ * CH * NPT;
    float*  A      = (float*)d_ws;                       // BCN f32: t2
    float*  Bb     = A + BCN;                            // BCN f32: featP (bf16) -> u
    unsigned short* featP = (unsigned short*)Bb;
    float*  Cc     = Bb + BCN;                           // 2*BCN f32: t1d (f64) -> hcat
    double* t1d    = (double*)Cc;
    double* featT  = (double*)(Cc + 2 * BCN);            // BCN f64
    float*  feat32 = (float*)(featT + BCN);              // BCN f32
    float*  sqv    = feat32 + BCN;                       // B*N
    int*    idxh   = (int*)(sqv + (size_t)BSZ * NPT);    // B*N*40
    int*    idxf   = idxh + (size_t)BSZ * NPT * KCAND;   // B*N*16
    float*  bnacc  = (float*)(idxf + (size_t)BSZ * NPT * KNB);  // 4*CH f32
    float *s1sum = bnacc, *s1sq = bnacc + CH, *s2sum = bnacc + 2 * CH, *s2sq = bnacc + 3 * CH;
    double* scd    = (double*)(bnacc + 4 * CH);
    float*  scb    = (float*)(scd + CH);
    float *sc0 = scb, *sh0 = scb + CH;

    dim3 gg(NPT / 1024, CH / 8, BSZ);
    dim3 ge(NPT / 1024, CH, BSZ);

    hipMemsetAsync(bnacc, 0, 4 * CH * sizeof(float), stream);
    // fc1 (f64 accumulate)
    k_fc1_f64<<<gg, 256, 0, stream>>>(x, w1, t1d);
    // BN0 stats in f64
    k_stats_f64<<<CH, 256, 0, stream>>>(t1d, g0, b0, sc0, sh0, scd);
    // fused transpose/scale -> featT + feat32 + featP(fragment layout) + sqv
    k_feat<<<dim3(NPT / 32, BSZ), dim3(32, 8), 0, stream>>>(t1d, scd, featT, feat32, featP, sqv);
    // kNN prefilter (lane-contiguous fragment loads)
    k_knn_mfma<<<dim3(2 * NPT / 64, BSZ), 512, 0, stream>>>(featP, sqv, idxh);
    // fused refine v3 (chunked ILP, no spill, certified f64 fallback)
    k_refine<<<dim3(NPT / 4, BSZ), 256, 0, stream>>>(feat32, featT, idxh, idxf);
    // gather (coalesced; writes hcat over dead t1d)
    k_gather2<<<dim3(NPT / 32, 2, BSZ), 128, 0, stream>>>(feat32, sh0, idxf, Cc);
    // mr conv + bias + BN1-stat atomics
    k_gemm_mr<<<gg, 256, 0, stream>>>(Cc, wmr, bmr, A, s1sum, s1sq);
    // u = gelu(gelu(BN1(t2))) + BN2-stat atomics
    k_u<<<ge, 256, 0, stream>>>(A, s1sum, s1sq, gm, bm, Bb, s2sum, s2sq);
    // fc2 with BN2 folded + residual
    k_gemm_fc2<<<gg, 256, 0, stream>>>(Bb, w2, s2sum, s2sq, g1, b1, x, outp);
}

// Round 16
// 431.522 us; speedup vs baseline: 1.1775x; 1.1186x over previous
//
#include <hip/hip_runtime.h>
#include <hip/hip_bf16.h>
#include <math.h>

#define BSZ 4
#define NPT 4096
#define CH  192
#define KNB 16
#define KPH 16              // kept per half (top-16/half provably suffices)
#define KCAND (2 * KPH)     // 32 refine candidates
#define NTOT ((float)(BSZ * NPT))

typedef short short8 __attribute__((ext_vector_type(8)));
typedef float f32x4  __attribute__((ext_vector_type(4)));

__device__ __forceinline__ float gelu_exact(float x){
    return 0.5f * x * (1.0f + erff(x * 0.70710678118654752440f));
}
__device__ __forceinline__ unsigned int umin_(unsigned int a, unsigned int b){ return a < b ? a : b; }
__device__ __forceinline__ unsigned int umax_(unsigned int a, unsigned int b){ return a < b ? b : a; }
__device__ __forceinline__ unsigned short bf16rnd(float v){
    unsigned int bits = __builtin_bit_cast(unsigned int, v);
    return (unsigned short)((bits + 0x7fff + ((bits >> 16) & 1)) >> 16);
}

// ---------------- fc1 with f64 accumulation -> f64 t1 -------------------------------------------
__global__ __launch_bounds__(256) void k_fc1_f64(
    const float* __restrict__ in, const float* __restrict__ W, double* __restrict__ outd)
{
    constexpr int OT = 8, NT = 4;
    __shared__ float wtT[CH][OT];
    const int tid = threadIdx.x;
    const int o0  = blockIdx.y * OT;
    const int b   = blockIdx.z;
    const int n   = blockIdx.x * (256 * NT) + tid * NT;

    for (int lin = tid; lin < CH * OT; lin += 256){
        int c = lin >> 3, o = lin & 7;
        wtT[c][o] = W[(size_t)(o0 + o) * CH + c];
    }
    __syncthreads();

    double acc[OT][NT] = {};
    const float* ip = in + (size_t)b * CH * NPT + n;
    for (int c = 0; c < CH; ++c){
        float4 x4 = *reinterpret_cast<const float4*>(ip + (size_t)c * NPT);
        double xv[NT] = {x4.x, x4.y, x4.z, x4.w};
        float4 w0 = *reinterpret_cast<const float4*>(&wtT[c][0]);
        float4 w1 = *reinterpret_cast<const float4*>(&wtT[c][4]);
        double wv[OT] = {w0.x, w0.y, w0.z, w0.w, w1.x, w1.y, w1.z, w1.w};
        #pragma unroll
        for (int oo = 0; oo < OT; ++oo)
            #pragma unroll
            for (int j = 0; j < NT; ++j)
                acc[oo][j] = fma(wv[oo], xv[j], acc[oo][j]);
    }

    #pragma unroll
    for (int oo = 0; oo < OT; ++oo){
        size_t off = ((size_t)b * CH + o0 + oo) * NPT + n;
        #pragma unroll
        for (int j = 0; j < 4; ++j) outd[off + j] = acc[oo][j];
    }
}

// ---------------- f64 BN0 stats: fp32 scale/shift + f64 scale -----------------------------------
__global__ __launch_bounds__(256) void k_stats_f64(
    const double* __restrict__ t, const float* __restrict__ gamma,
    const float* __restrict__ beta, float* __restrict__ scale,
    float* __restrict__ shift, double* __restrict__ scd)
{
    const int c = blockIdx.x, tid = threadIdx.x;
    double s = 0., s2 = 0.;
    for (int b = 0; b < BSZ; ++b){
        const double* p = t + ((size_t)b * CH + c) * NPT;
        for (int n = tid; n < NPT; n += 256){ double v = p[n]; s += v; s2 += v * v; }
    }
    __shared__ double rs[256], rs2[256];
    rs[tid] = s; rs2[tid] = s2; __syncthreads();
    for (int off = 128; off; off >>= 1){
        if (tid < off){ rs[tid] += rs[tid + off]; rs2[tid] += rs2[tid + off]; }
        __syncthreads();
    }
    if (tid == 0){
        const double invn = 1.0 / (BSZ * NPT);
        double mean = rs[0] * invn;
        double var  = rs2[0] * invn - mean * mean;
        double rstd = 1.0 / sqrt(var + 1e-5);
        double s_   = rstd * (double)gamma[c];
        scale[c] = (float)s_;
        shift[c] = (float)((double)beta[c] - mean * s_);
        scd[c]   = s_;
    }
}

// ---------------- fused: transpose+scale -> featT(f64), feat32, featP (MFMA-fragment bf16), sqv -
__global__ void k_feat(
    const double* __restrict__ t1d, const double* __restrict__ scd,
    double* __restrict__ featT, float* __restrict__ feat32,
    unsigned short* __restrict__ featP, float* __restrict__ sqv)
{
    __shared__ double tile[32][33];
    __shared__ float sqp[32][33];
    const int n0 = blockIdx.x * 32, b = blockIdx.y;
    const int tx = threadIdx.x, ty = threadIdx.y;
    const int tid = ty * 32 + tx;
    float part[4] = {0.f, 0.f, 0.f, 0.f};
    unsigned short* fpb = featP + (size_t)b * NPT * CH;

    for (int cc = 0; cc < CH / 32; ++cc){
        const int cbase = cc * 32;
        #pragma unroll
        for (int r = 0; r < 32; r += 8){
            int c = cbase + ty + r;
            tile[ty + r][tx] = t1d[((size_t)b * CH + c) * NPT + n0 + tx] * scd[c];
        }
        __syncthreads();
        #pragma unroll
        for (int r = 0; r < 32; r += 8){
            int n = n0 + ty + r;
            int c = cbase + tx;
            double v = tile[tx][ty + r];
            size_t o = ((size_t)b * NPT + n) * CH + c;
            featT[o] = v;
            float f = (float)v;
            feat32[o] = f;
            part[r >> 3] = fmaf(f, f, part[r >> 3]);
        }
        if (tid < 128){
            const int t_ = tid >> 6;
            const int l  = tid & 63;
            const int r_ = l & 15, g_ = l >> 4;
            const int nl = t_ * 16 + r_;
            short8 pk;
            #pragma unroll
            for (int e = 0; e < 8; ++e)
                pk[e] = (short)bf16rnd((float)tile[g_ * 8 + e][nl]);
            const int tP = blockIdx.x * 2 + t_;
            *reinterpret_cast<short8*>(fpb + (size_t)(tP * 6 + cc) * 512 + l * 8) = pk;
        }
        __syncthreads();
    }
    #pragma unroll
    for (int j = 0; j < 4; ++j) sqp[ty + 8 * j][tx] = part[j];
    __syncthreads();
    if (ty == 0){
        float s = 0.f;
        #pragma unroll 8
        for (int k = 0; k < 32; ++k) s += sqp[tx][k];
        sqv[b * NPT + n0 + tx] = s;
    }
}

// ---------------- MFMA kNN prefilter v10: lane-contiguous fragment loads ------------------------
__global__ __launch_bounds__(512, 4) void k_knn_mfma(
    const unsigned short* __restrict__ featP, const float* __restrict__ sqv,
    int* __restrict__ idxh)
{
    __shared__ unsigned int mlist[8][16][17];
    const int tid  = threadIdx.x;
    const int wv   = tid >> 6;
    const int lane = tid & 63;
    const int r = lane & 15, g = lane >> 4;
    const int b    = blockIdx.y;
    const int qt   = blockIdx.x >> 1;
    const int half = blockIdx.x & 1;
    const int qs = wv >> 1, mq = wv & 1;
    const int tq   = qt * 4 + qs;
    const int tm0  = half * 128 + mq * 64;
    const unsigned short* fp = featP + (size_t)b * NPT * CH;

    short8 bq0, bq1, bq2, bq3, bq4, bq5;
    {
        const unsigned short* qp = fp + (size_t)tq * 3072 + lane * 8;
        bq0 = *reinterpret_cast<const short8*>(qp);
        bq1 = *reinterpret_cast<const short8*>(qp + 512);
        bq2 = *reinterpret_cast<const short8*>(qp + 1024);
        bq3 = *reinterpret_cast<const short8*>(qp + 1536);
        bq4 = *reinterpret_cast<const short8*>(qp + 2048);
        bq5 = *reinterpret_cast<const short8*>(qp + 2560);
    }

    unsigned int Q[16];
    #pragma unroll
    for (int e = 0; e < 16; ++e) Q[e] = 0xFFFFFFFFu;

    const float* sq = sqv + b * NPT;
    const unsigned short* pa = fp + (size_t)tm0 * 3072 + lane * 8;

    for (int it = 0; it < 64; ++it){
        const unsigned short* p = pa + (size_t)it * 3072;
        short8 a0 = *reinterpret_cast<const short8*>(p);
        short8 a1 = *reinterpret_cast<const short8*>(p + 512);
        short8 a2 = *reinterpret_cast<const short8*>(p + 1024);
        short8 a3 = *reinterpret_cast<const short8*>(p + 1536);
        short8 a4 = *reinterpret_cast<const short8*>(p + 2048);
        short8 a5 = *reinterpret_cast<const short8*>(p + 2560);
        const int tm = tm0 + it;
        float4 s4 = *reinterpret_cast<const float4*>(sq + tm * 16 + 4 * g);

        f32x4 acc = {0.f, 0.f, 0.f, 0.f};
        acc = __builtin_amdgcn_mfma_f32_16x16x32_bf16(a0, bq0, acc, 0, 0, 0);
        acc = __builtin_amdgcn_mfma_f32_16x16x32_bf16(a1, bq1, acc, 0, 0, 0);
        acc = __builtin_amdgcn_mfma_f32_16x16x32_bf16(a2, bq2, acc, 0, 0, 0);
        acc = __builtin_amdgcn_mfma_f32_16x16x32_bf16(a3, bq3, acc, 0, 0, 0);
        acc = __builtin_amdgcn_mfma_f32_16x16x32_bf16(a4, bq4, acc, 0, 0, 0);
        acc = __builtin_amdgcn_mfma_f32_16x16x32_bf16(a5, bq5, acc, 0, 0, 0);

        const int m0 = tm * 16 + 4 * g;
        float sa[4] = {s4.x, s4.y, s4.z, s4.w};
        #pragma unroll
        for (int u = 0; u < 4; ++u){
            float d = fmaf(-2.0f, acc[u], sa[u]);
            int bb = __builtin_bit_cast(int, d);
            unsigned int uu = (unsigned int)(bb ^ ((bb >> 31) | 0x80000000));
            unsigned int k  = (uu & 0xFFFFF000u) | (unsigned int)(m0 + u);
            #pragma unroll
            for (int e = 0; e < 16; ++e){
                unsigned int qe = Q[e];
                Q[e] = umin_(k, qe);
                k    = umax_(k, qe);
            }
        }
    }

    #pragma unroll 1
    for (int rd = 0; rd < 16; ++rd){
        unsigned int v = Q[0];
        v = umin_(v, (unsigned int)__shfl_xor((int)v, 16));
        v = umin_(v, (unsigned int)__shfl_xor((int)v, 32));
        bool win = (Q[0] == v);
        if (win){
            #pragma unroll
            for (int e = 0; e < 15; ++e) Q[e] = Q[e + 1];
            Q[15] = 0xFFFFFFFFu;
        }
        if (g == 0) mlist[wv][r][rd] = v;
    }
    if (g == 0) mlist[wv][r][16] = 0xFFFFFFFFu;
    __syncthreads();

    // merge the 2 m-quarter wave-lists per query -> top-16 for this half (keys unique)
    if (tid < 64){
        const int qsub = tid >> 4, rr = tid & 15;
        int i0 = 0, i1 = 0;
        int* op = idxh + ((size_t)(b * NPT + qt * 64 + qsub * 16 + rr) * 2 + half) * KPH;
        for (int rd = 0; rd < KPH; ++rd){
            unsigned int k0 = mlist[qsub * 2][rr][i0];
            unsigned int k1 = mlist[qsub * 2 + 1][rr][i1];
            unsigned int mm = umin_(k0, k1);
            op[rd] = (int)(mm & 0xFFFu);
            i0 += (k0 == mm); i1 += (k1 == mm);
        }
    }
}

// ---------------- fused refine v4: 2 queries/wave, 32-lane groups, certified f64 fallback -------
// block 256 = 4 waves = 8 queries. Group = 32 lanes; lane sl handles ch sl + 32*j (j=0..5).
// Chunks of 8 candidates (48 loads in flight/lane-group); KCAND=32 maps onto the 32 lane slots.
__global__ __launch_bounds__(256) void k_refine(
    const float* __restrict__ feat32, const double* __restrict__ featT,
    const int* __restrict__ idxh, int* __restrict__ idxf)
{
    const int q = blockIdx.x * 8 + (threadIdx.x >> 5);
    const int b = blockIdx.y;
    const int sl = threadIdx.x & 31;
    const int* cl = idxh + ((size_t)b * NPT + q) * KCAND;
    const float* qv = feat32 + ((size_t)b * NPT + q) * CH;
    float qr[6];
    #pragma unroll
    for (int j = 0; j < 6; ++j) qr[j] = qv[sl + 32 * j];

    float myd = INFINITY; int mym = 0x7fffffff;
    #pragma unroll
    for (int t0 = 0; t0 < KCAND; t0 += 8){
        float pd[8]; int cm[8];
        #pragma unroll
        for (int j = 0; j < 8; ++j){
            int m = cl[t0 + j];
            cm[j] = m;
            const float* cv = feat32 + ((size_t)b * NPT + m) * CH;
            float d = 0.f;
            #pragma unroll
            for (int e = 0; e < 6; ++e){
                float dv = cv[sl + 32 * e] - qr[e];
                d = fmaf(dv, dv, d);
            }
            pd[j] = d;
        }
        #pragma unroll
        for (int j = 0; j < 8; ++j){
            float d = pd[j];
            #pragma unroll
            for (int off = 16; off; off >>= 1) d += __shfl_xor(d, off, 32);
            if (sl == t0 + j){ myd = d; mym = cm[j]; }
        }
    }

    float d16 = 0.f;
    for (int r = 0; r < KNB; ++r){
        float bv = myd; int bi = mym;
        #pragma unroll
        for (int off = 16; off; off >>= 1){
            float ov = __shfl_xor(bv, off, 32);
            int   oi = __shfl_xor(bi, off, 32);
            if (ov < bv || (ov == bv && oi < bi)){ bv = ov; bi = oi; }
        }
        if (sl == 0) idxf[((size_t)b * NPT + q) * KNB + r] = bi;
        if (mym == bi){ myd = INFINITY; mym = 0x7fffffff; }
        d16 = bv;
    }
    float b17 = myd;
    #pragma unroll
    for (int off = 16; off; off >>= 1) b17 = fminf(b17, __shfl_xor(b17, off, 32));
    int flag = (b17 - d16 < 1e-3f + 2e-4f * d16) ? 1 : 0;
    flag = __shfl(flag, 0, 32);
    if (!flag) return;

    // exact f64 re-rank (rare; 32-lane group)
    const double* qvd = featT + ((size_t)b * NPT + q) * CH;
    double qrd[6];
    #pragma unroll
    for (int j = 0; j < 6; ++j) qrd[j] = qvd[sl + 32 * j];
    double mydd = INFINITY; int mymd = 0x7fffffff;
    for (int t = 0; t < KCAND; ++t){
        int m = cl[t];
        const double* cv = featT + ((size_t)b * NPT + m) * CH;
        double d = 0.;
        #pragma unroll
        for (int e = 0; e < 6; ++e){
            double dv = cv[sl + 32 * e] - qrd[e];
            d = fma(dv, dv, d);
        }
        #pragma unroll
        for (int off = 16; off; off >>= 1) d += __shfl_xor(d, off, 32);
        if (sl == t){ mydd = d; mymd = m; }
    }
    for (int r = 0; r < KNB; ++r){
        double bv = mydd; int bi = mymd;
        #pragma unroll
        for (int off = 16; off; off >>= 1){
            double ov = __shfl_xor(bv, off, 32);
            int    oi = __shfl_xor(bi, off, 32);
            if (ov < bv || (ov == bv && oi < bi)){ bv = ov; bi = oi; }
        }
        if (sl == 0) idxf[((size_t)b * NPT + q) * KNB + r] = bi;
        if (mymd == bi){ mydd = INFINITY; mymd = 0x7fffffff; }
    }
}

// ---------------- gather v2: coalesced rows + LDS-transposed hcat write -------------------------
__global__ __launch_bounds__(128) void k_gather2(
    const float* __restrict__ feat32, const float* __restrict__ sh0,
    const int* __restrict__ idx, float* __restrict__ hcat)
{
    __shared__ float lt[192 * 33];
    __shared__ int il[32 * KNB];
    const int tid = threadIdx.x;
    const int n0  = blockIdx.x * 32;
    const int cg  = blockIdx.y;
    const int b   = blockIdx.z;

    for (int i = tid; i < 32 * KNB; i += 128)
        il[i] = idx[((size_t)b * NPT + n0) * KNB + i];
    __syncthreads();

    const int nl = tid >> 2, sub = tid & 3;
    const int n  = n0 + nl;
    const float* fbase = feat32 + (size_t)b * NPT * CH;
    const float* qr = fbase + (size_t)n * CH + cg * 96;

    float4 qv[6], mx[6];
    #pragma unroll
    for (int j = 0; j < 6; ++j){
        qv[j] = *reinterpret_cast<const float4*>(qr + (sub + 4 * j) * 4);
        mx[j] = make_float4(-INFINITY, -INFINITY, -INFINITY, -INFINITY);
    }

    #pragma unroll 4
    for (int k = 0; k < KNB; ++k){
        const float* cr = fbase + (size_t)il[nl * KNB + k] * CH + cg * 96;
        #pragma unroll
        for (int j = 0; j < 6; ++j){
            float4 v = *reinterpret_cast<const float4*>(cr + (sub + 4 * j) * 4);
            mx[j].x = fmaxf(mx[j].x, v.x - qv[j].x);
            mx[j].y = fmaxf(mx[j].y, v.y - qv[j].y);
            mx[j].z = fmaxf(mx[j].z, v.z - qv[j].z);
            mx[j].w = fmaxf(mx[j].w, v.w - qv[j].w);
        }
    }

    #pragma unroll
    for (int j = 0; j < 6; ++j){
        const int cb = (sub + 4 * j) * 4;
        float4 s4 = *reinterpret_cast<const float4*>(sh0 + cg * 96 + cb);
        float fi[4] = {qv[j].x + s4.x, qv[j].y + s4.y, qv[j].z + s4.z, qv[j].w + s4.w};
        float mm[4] = {mx[j].x, mx[j].y, mx[j].z, mx[j].w};
        #pragma unroll
        for (int e = 0; e < 4; ++e){
            int cl = cb + e;
            lt[(2 * cl) * 33 + nl]     = fi[e];
            lt[(2 * cl + 1) * 33 + nl] = mm[e];
        }
    }
    __syncthreads();

    const int rsub = tid >> 5;
    const int ni   = tid & 31;
    for (int r0 = 0; r0 < 192; r0 += 4){
        int row = r0 + rsub;
        int ch  = cg * 192 + row;
        hcat[((size_t)b * 2 * CH + ch) * NPT + n0 + ni] = lt[row * 33 + ni];
    }
}

// ---------------- mr-conv GEMM (K=384) + bias, with fused BN1-stat atomics ----------------------
__global__ __launch_bounds__(256) void k_gemm_mr(
    const float* __restrict__ in, const float* __restrict__ W, const float* __restrict__ bias,
    float* __restrict__ out, float* __restrict__ s1sum, float* __restrict__ s1sq)
{
    constexpr int KDIM = 2 * CH, OT = 8, NT = 4;
    __shared__ float wtT[KDIM][OT];
    __shared__ float redS[4][8], redQ[4][8];
    const int tid = threadIdx.x;
    const int o0  = blockIdx.y * OT;
    const int b   = blockIdx.z;
    const int n   = blockIdx.x * (256 * NT) + tid * NT;

    for (int lin = tid; lin < KDIM * OT; lin += 256){
        int c = lin >> 3, o = lin & 7;
        wtT[c][o] = W[(size_t)(o0 + o) * KDIM + c];
    }
    __syncthreads();

    float acc[OT][NT] = {};
    const float* ip = in + (size_t)b * KDIM * NPT + n;
    #pragma unroll 2
    for (int c = 0; c < KDIM; ++c){
        float4 x4 = *reinterpret_cast<const float4*>(ip + (size_t)c * NPT);
        float xv[NT] = {x4.x, x4.y, x4.z, x4.w};
        float4 w0 = *reinterpret_cast<const float4*>(&wtT[c][0]);
        float4 w1 = *reinterpret_cast<const float4*>(&wtT[c][4]);
        float wv[OT] = {w0.x, w0.y, w0.z, w0.w, w1.x, w1.y, w1.z, w1.w};
        #pragma unroll
        for (int oo = 0; oo < OT; ++oo)
            #pragma unroll
            for (int j = 0; j < NT; ++j)
                acc[oo][j] = fmaf(wv[oo], xv[j], acc[oo][j]);
    }

    float ps[OT], pq[OT];
    #pragma unroll
    for (int oo = 0; oo < OT; ++oo){
        size_t off = ((size_t)b * CH + o0 + oo) * NPT + n;
        float add = bias[o0 + oo];
        float vals[4];
        float s = 0.f, q = 0.f;
        #pragma unroll
        for (int j = 0; j < 4; ++j){
            vals[j] = acc[oo][j] + add;
            s += vals[j];
            q = fmaf(vals[j], vals[j], q);
        }
        ps[oo] = s; pq[oo] = q;
        float4 o4; o4.x = vals[0]; o4.y = vals[1]; o4.z = vals[2]; o4.w = vals[3];
        *reinterpret_cast<float4*>(out + off) = o4;
    }

    #pragma unroll
    for (int oo = 0; oo < OT; ++oo){
        #pragma unroll
        for (int off = 32; off; off >>= 1){
            ps[oo] += __shfl_xor(ps[oo], off);
            pq[oo] += __shfl_xor(pq[oo], off);
        }
    }
    const int wv = tid >> 6, lane = tid & 63;
    if (lane == 0){
        #pragma unroll
        for (int oo = 0; oo < OT; ++oo){ redS[wv][oo] = ps[oo]; redQ[wv][oo] = pq[oo]; }
    }
    __syncthreads();
    if (tid < 8){
        float s = redS[0][tid] + redS[1][tid] + redS[2][tid] + redS[3][tid];
        float q = redQ[0][tid] + redQ[1][tid] + redQ[2][tid] + redQ[3][tid];
        atomicAdd(&s1sum[o0 + tid], s);
        atomicAdd(&s1sq[o0 + tid], q);
    }
}

// ---------------- u = gelu(gelu(BN1(t2))), BN1 from sums; fused BN2-stat atomics ----------------
__global__ __launch_bounds__(256) void k_u(
    const float* __restrict__ in, const float* __restrict__ s1sum, const float* __restrict__ s1sq,
    const float* __restrict__ gm, const float* __restrict__ bm,
    float* __restrict__ out, float* __restrict__ s2sum, float* __restrict__ s2sq)
{
    __shared__ float redS[4], redQ[4];
    const int c = blockIdx.y, b = blockIdx.z;
    const int n = (blockIdx.x * 256 + threadIdx.x) * 4;
    const float invn = 1.0f / NTOT;
    float mean = s1sum[c] * invn;
    float var  = s1sq[c] * invn - mean * mean;
    float rstd = rsqrtf(var + 1e-5f);
    float s = rstd * gm[c], t = bm[c] - mean * s;

    size_t i = ((size_t)b * CH + c) * NPT + n;
    float4 v = *reinterpret_cast<const float4*>(in + i);
    float4 o;
    o.x = gelu_exact(gelu_exact(fmaf(v.x, s, t)));
    o.y = gelu_exact(gelu_exact(fmaf(v.y, s, t)));
    o.z = gelu_exact(gelu_exact(fmaf(v.z, s, t)));
    o.w = gelu_exact(gelu_exact(fmaf(v.w, s, t)));
    *reinterpret_cast<float4*>(out + i) = o;

    float ps = o.x + o.y + o.z + o.w;
    float pq = fmaf(o.x, o.x, fmaf(o.y, o.y, fmaf(o.z, o.z, o.w * o.w)));
    #pragma unroll
    for (int off = 32; off; off >>= 1){
        ps += __shfl_xor(ps, off);
        pq += __shfl_xor(pq, off);
    }
    const int wv = threadIdx.x >> 6, lane = threadIdx.x & 63;
    if (lane == 0){ redS[wv] = ps; redQ[wv] = pq; }
    __syncthreads();
    if (threadIdx.x == 0){
        atomicAdd(&s2sum[c], redS[0] + redS[1] + redS[2] + redS[3]);
        atomicAdd(&s2sq[c],  redQ[0] + redQ[1] + redQ[2] + redQ[3]);
    }
}

// ---------------- fc2 GEMM with BN2 (from sums) folded into input + residual --------------------
__global__ __launch_bounds__(256) void k_gemm_fc2(
    const float* __restrict__ in, const float* __restrict__ W,
    const float* __restrict__ s2sum, const float* __restrict__ s2sq,
    const float* __restrict__ g1, const float* __restrict__ b1,
    const float* __restrict__ resid, float* __restrict__ out)
{
    constexpr int KDIM = CH, OT = 8, NT = 4;
    __shared__ float wtT[KDIM][OT];
    __shared__ float scl[KDIM], shl[KDIM];
    const int tid = threadIdx.x;
    const int o0  = blockIdx.y * OT;
    const int b   = blockIdx.z;
    const int n   = blockIdx.x * (256 * NT) + tid * NT;

    for (int lin = tid; lin < KDIM * OT; lin += 256){
        int c = lin >> 3, o = lin & 7;
        wtT[c][o] = W[(size_t)(o0 + o) * KDIM + c];
    }
    const float invn = 1.0f / NTOT;
    for (int c = tid; c < KDIM; c += 256){
        float mean = s2sum[c] * invn;
        float var  = s2sq[c] * invn - mean * mean;
        float rstd = rsqrtf(var + 1e-5f);
        float s = rstd * g1[c];
        scl[c] = s;
        shl[c] = b1[c] - mean * s;
    }
    __syncthreads();

    float acc[OT][NT] = {};
    const float* ip = in + (size_t)b * KDIM * NPT + n;
    #pragma unroll 2
    for (int c = 0; c < KDIM; ++c){
        float4 x4 = *reinterpret_cast<const float4*>(ip + (size_t)c * NPT);
        float xv[NT];
        xv[0] = fmaf(x4.x, scl[c], shl[c]);
        xv[1] = fmaf(x4.y, scl[c], shl[c]);
        xv[2] = fmaf(x4.z, scl[c], shl[c]);
        xv[3] = fmaf(x4.w, scl[c], shl[c]);
        float4 w0 = *reinterpret_cast<const float4*>(&wtT[c][0]);
        float4 w1 = *reinterpret_cast<const float4*>(&wtT[c][4]);
        float wv[OT] = {w0.x, w0.y, w0.z, w0.w, w1.x, w1.y, w1.z, w1.w};
        #pragma unroll
        for (int oo = 0; oo < OT; ++oo)
            #pragma unroll
            for (int j = 0; j < NT; ++j)
                acc[oo][j] = fmaf(wv[oo], xv[j], acc[oo][j]);
    }

    #pragma unroll
    for (int oo = 0; oo < OT; ++oo){
        size_t off = ((size_t)b * CH + o0 + oo) * NPT + n;
        float4 r4 = *reinterpret_cast<const float4*>(resid + off);
        float4 o4;
        o4.x = acc[oo][0] + r4.x; o4.y = acc[oo][1] + r4.y;
        o4.z = acc[oo][2] + r4.z; o4.w = acc[oo][3] + r4.w;
        *reinterpret_cast<float4*>(out + off) = o4;
    }
}

extern "C" void kernel_launch(void* const* d_in, const int* in_sizes, int n_in,
                              void* d_out, int out_size, void* d_ws, size_t ws_size,
                              hipStream_t stream)
{
    const float* x    = (const float*)d_in[0];
    const float* w1   = (const float*)d_in[1];
    const float* w2   = (const float*)d_in[2];
    const float* wmr  = (const float*)d_in[3];
    const float* bmr  = (const float*)d_in[4];
    const float* g0   = (const float*)d_in[5];
    const float* b0   = (const float*)d_in[6];
    const float* gm   = (const float*)d_in[7];
    const float* bm   = (const float*)d_in[8];
    const float* g1   = (const float*)d_in[9];
    const float* b1   = (const float*)d_in[10];
    float* outp = (float*)d_out;

    const size_t BCN = (size_t)BSZ * CH * NPT;
    float*  A      = (float*)d_ws;                       // BCN f32: t2
    float*  Bb     = A + BCN;                            // BCN f32: featP (bf16) -> u
    unsigned short* featP = (unsigned short*)Bb;
    float*  Cc     = Bb + BCN;                           // 2*BCN f32: t1d (f64) -> hcat
    double* t1d    = (double*)Cc;
    double* featT  = (double*)(Cc + 2 * BCN);            // BCN f64
    float*  feat32 = (float*)(featT + BCN);              // BCN f32
    float*  sqv    = feat32 + BCN;                       // B*N
    int*    idxh   = (int*)(sqv + (size_t)BSZ * NPT);    // B*N*32
    int*    idxf   = idxh + (size_t)BSZ * NPT * KCAND;   // B*N*16
    float*  bnacc  = (float*)(idxf + (size_t)BSZ * NPT * KNB);  // 4*CH f32
    float *s1sum = bnacc, *s1sq = bnacc + CH, *s2sum = bnacc + 2 * CH, *s2sq = bnacc + 3 * CH;
    double* scd    = (double*)(bnacc + 4 * CH);
    float*  scb    = (float*)(scd + CH);
    float *sc0 = scb, *sh0 = scb + CH;

    dim3 gg(NPT / 1024, CH / 8, BSZ);
    dim3 ge(NPT / 1024, CH, BSZ);

    hipMemsetAsync(bnacc, 0, 4 * CH * sizeof(float), stream);
    // fc1 (f64 accumulate)
    k_fc1_f64<<<gg, 256, 0, stream>>>(x, w1, t1d);
    // BN0 stats in f64
    k_stats_f64<<<CH, 256, 0, stream>>>(t1d, g0, b0, sc0, sh0, scd);
    // fused transpose/scale -> featT + feat32 + featP(fragment layout) + sqv
    k_feat<<<dim3(NPT / 32, BSZ), dim3(32, 8), 0, stream>>>(t1d, scd, featT, feat32, featP, sqv);
    // kNN prefilter (lane-contiguous fragment loads, top-16/half)
    k_knn_mfma<<<dim3(2 * NPT / 64, BSZ), 512, 0, stream>>>(featP, sqv, idxh);
    // fused refine v4 (2 q/wave, 32-candidate, certified f64 fallback)
    k_refine<<<dim3(NPT / 8, BSZ), 256, 0, stream>>>(feat32, featT, idxh, idxf);
    // gather (coalesced; writes hcat over dead t1d)
    k_gather2<<<dim3(NPT / 32, 2, BSZ), 128, 0, stream>>>(feat32, sh0, idxf, Cc);
    // mr conv + bias + BN1-stat atomics
    k_gemm_mr<<<gg, 256, 0, stream>>>(Cc, wmr, bmr, A, s1sum, s1sq);
    // u = gelu(gelu(BN1(t2))) + BN2-stat atomics
    k_u<<<ge, 256, 0, stream>>>(A, s1sum, s1sq, gm, bm, Bb, s2sum, s2sq);
    // fc2 with BN2 folded + residual
    k_gemm_fc2<<<gg, 256, 0, stream>>>(Bb, w2, s2sum, s2sq, g1, b1, x, outp);
}